// Round 8
// baseline (1207.881 us; speedup 1.0000x reference)
//
#include <hip/hip_runtime.h>

#define NN 50000
#define NE 800000
#define D 128
#define NCLS 47
#define ZPAD 64   // padded width for projected layer-2 features
#define LN_EPS 1e-5f

// ---------------- CSR build ----------------
__global__ void k_count(const int* __restrict__ dst, int* __restrict__ counts) {
  int i = blockIdx.x * blockDim.x + threadIdx.x;
  if (i < NE) atomicAdd(&counts[dst[i]], 1);
}

__global__ void k_scan1(const int* __restrict__ counts, int* __restrict__ excl,
                        int* __restrict__ bsum) {
  __shared__ int tmp[256];
  int t = threadIdx.x, i = blockIdx.x * 256 + t;
  int v = (i < NN) ? counts[i] : 0;
  tmp[t] = v;
  __syncthreads();
  for (int off = 1; off < 256; off <<= 1) {
    int u = (t >= off) ? tmp[t - off] : 0;
    __syncthreads();
    tmp[t] += u;
    __syncthreads();
  }
  if (i < NN) excl[i] = tmp[t] - v;
  if (t == 255) bsum[blockIdx.x] = tmp[255];
}

__global__ void k_scan2(int* __restrict__ bsum, int nb) {
  __shared__ int tmp[256];
  int t = threadIdx.x;
  int v = (t < nb) ? bsum[t] : 0;
  tmp[t] = v;
  __syncthreads();
  for (int off = 1; off < 256; off <<= 1) {
    int u = (t >= off) ? tmp[t - off] : 0;
    __syncthreads();
    tmp[t] += u;
    __syncthreads();
  }
  if (t < nb) bsum[t] = tmp[t] - v;
}

__global__ void k_scan3(int* __restrict__ indptr, const int* __restrict__ bsum,
                        int* __restrict__ cursor) {
  int i = blockIdx.x * 256 + threadIdx.x;
  if (i < NN) {
    int v = indptr[i] + bsum[i >> 8];
    indptr[i] = v;
    cursor[i] = v;
  }
  if (i == 0) indptr[NN] = NE;
}

__global__ void k_scatter(const int* __restrict__ src, const int* __restrict__ dst,
                          int* __restrict__ cursor, int* __restrict__ esrc) {
  int i = blockIdx.x * blockDim.x + threadIdx.x;
  if (i < NE) {
    int d = dst[i];
    int pos = atomicAdd(&cursor[d], 1);
    esrc[pos] = src[i];
  }
}

// ---------------- mean aggregation (128-wide), XCD column-sliced ----------------
// slice = blockIdx.x & 7 -> XCD (round-robin dispatch); slice covers 16 cols.
// Per-XCD feature working set = 50000*16*4B = 3.2 MB -> L2-resident.
// 16-lane group per node; 8 edges in flight per group.
__global__ __launch_bounds__(256) void k_agg(const float* __restrict__ feat,
                                             const int* __restrict__ indptr,
                                             const int* __restrict__ esrc,
                                             float* __restrict__ out) {
  int bid = blockIdx.x;
  int slice = bid & 7;
  int chunk = bid >> 3;
  int tid = threadIdx.x;
  int node = chunk * 16 + (tid >> 4);
  if (node >= NN) return;
  int col = (slice << 4) | (tid & 15);
  const float* fcol = feat + col;
  int beg = indptr[node], end = indptr[node + 1];
  float a = 0.f;
  int e = beg;
  for (; e + 7 < end; e += 8) {  // 8 gathers in flight
    int idx[8];
#pragma unroll
    for (int j = 0; j < 8; ++j) idx[j] = esrc[e + j];
    float v[8];
#pragma unroll
    for (int j = 0; j < 8; ++j) v[j] = fcol[(size_t)idx[j] * D];
#pragma unroll
    for (int j = 0; j < 8; ++j) a += v[j];
  }
  for (; e < end; ++e) a += fcol[(size_t)esrc[e] * D];
  float inv = 1.0f / fmaxf((float)(end - beg), 1.0f);
  out[(size_t)node * D + col] = a * inv;
}

// ---------------- fused dual-GEMM + LN + ReLU (hidden layers) ----------------
// 32 rows/block (32 KB LDS, 5 blocks/CU = 160 KB), 256 thr (4 waves), wave
// handles 8 rows, lane j owns output cols j and j+64. Per chunk: batch all 8
// rows' ds_read_b128 first, then 64 FMAs. Weights software-pipelined 1 ahead.
__global__ __launch_bounds__(256, 5) void k_gemm_ln(
    const float* __restrict__ h, const float* __restrict__ hn,
    const float* __restrict__ ws, const float* __restrict__ wn,
    const float* __restrict__ b, const float* __restrict__ g,
    const float* __restrict__ be, float* __restrict__ out) {
  __shared__ float lds[32][256];  // cols [0,128)=h, [128,256)=hn (32 KB)
  int tid = threadIdx.x;
  int row0 = blockIdx.x * 32;
  for (int i = tid; i < 32 * 64; i += 256) {  // float4 granules, 64 per row
    int r = i >> 6, q = i & 63;
    int row = row0 + r;
    float4 v = make_float4(0.f, 0.f, 0.f, 0.f);
    if (row < NN) {
      const float* p = (q < 32) ? (h + (size_t)row * D + q * 4)
                                : (hn + (size_t)row * D + (q - 32) * 4);
      v = *(const float4*)p;
    }
    *(float4*)&lds[r][q * 4] = v;
  }
  __syncthreads();

  int wv = tid >> 6, lane = tid & 63;
  int rbase = wv * 8;
  float acc0[8], acc1[8];
#pragma unroll
  for (int r = 0; r < 8; ++r) { acc0[r] = 0.f; acc1[r] = 0.f; }

  // 64 chunks of 4 k-rows: c in [0,32) -> ws, [32,64) -> wn; lds col = c*4.
  float cw[8], nw[8];
#pragma unroll
  for (int j = 0; j < 4; ++j) {  // preload chunk 0 (self rows 0..3)
    cw[2 * j]     = ws[j * 128 + lane];
    cw[2 * j + 1] = ws[j * 128 + lane + 64];
  }
#pragma unroll 2
  for (int c = 0; c < 64; ++c) {
    int cn = (c + 1 < 64) ? c + 1 : 63;  // last iter: harmless reload
    const float* np = ((cn & 32) ? wn : ws) + (cn & 31) * 512;
    // batch-load current chunk's 8 rows -> 8 ds_read_b128 in flight
    float4 hv[8];
#pragma unroll
    for (int r = 0; r < 8; ++r) hv[r] = *(const float4*)&lds[rbase + r][c * 4];
    // prefetch next chunk's weights (8 global loads in flight over the FMAs)
#pragma unroll
    for (int j = 0; j < 4; ++j) {
      nw[2 * j]     = np[j * 128 + lane];
      nw[2 * j + 1] = np[j * 128 + lane + 64];
    }
#pragma unroll
    for (int r = 0; r < 8; ++r) {
      acc0[r] = fmaf(hv[r].x, cw[0], acc0[r]);
      acc1[r] = fmaf(hv[r].x, cw[1], acc1[r]);
      acc0[r] = fmaf(hv[r].y, cw[2], acc0[r]);
      acc1[r] = fmaf(hv[r].y, cw[3], acc1[r]);
      acc0[r] = fmaf(hv[r].z, cw[4], acc0[r]);
      acc1[r] = fmaf(hv[r].z, cw[5], acc1[r]);
      acc0[r] = fmaf(hv[r].w, cw[6], acc0[r]);
      acc1[r] = fmaf(hv[r].w, cw[7], acc1[r]);
    }
#pragma unroll
    for (int j = 0; j < 8; ++j) cw[j] = nw[j];
  }

  float bj0 = b[lane], bj1 = b[lane + 64];
  float gj0 = g[lane], gj1 = g[lane + 64];
  float ej0 = be[lane], ej1 = be[lane + 64];
#pragma unroll
  for (int r = 0; r < 8; ++r) {
    float v0 = acc0[r] + bj0, v1 = acc1[r] + bj1;
    float s = v0 + v1, q2 = v0 * v0 + v1 * v1;
#pragma unroll
    for (int off = 1; off < 64; off <<= 1) {
      s += __shfl_xor(s, off, 64);
      q2 += __shfl_xor(q2, off, 64);
    }
    float mu = s * (1.0f / 128.0f);
    float var = q2 * (1.0f / 128.0f) - mu * mu;
    float rs = rsqrtf(var + LN_EPS);
    float o0 = fmaxf((v0 - mu) * rs * gj0 + ej0, 0.f);
    float o1 = fmaxf((v1 - mu) * rs * gj1 + ej1, 0.f);
    int row = row0 + rbase + r;
    if (row < NN) {
      out[(size_t)row * D + lane] = o0;
      out[(size_t)row * D + lane + 64] = o1;
    }
  }
}

// ---------------- layer 2: project h2 through BOTH weight matrices ----------------
// s2p[row][j] = (h2 @ w_self2)[row][j] + b2[j]   (j < 47)
// z2 [row][j] = (h2 @ w_neigh2)[row][j]          (j < 47; cols 47..63 zeroed)
__global__ __launch_bounds__(256, 8) void k_gemm_proj2(
    const float* __restrict__ h, const float* __restrict__ ws,
    const float* __restrict__ wn, const float* __restrict__ b,
    float* __restrict__ s2p, float* __restrict__ z2) {
  __shared__ float lds[32][128];  // 16 KB
  int tid = threadIdx.x;
  int row0 = blockIdx.x * 32;
  for (int i = tid; i < 32 * 32; i += 256) {  // float4 granules, 32 per row
    int r = i >> 5, q = i & 31;
    int row = row0 + r;
    float4 v = make_float4(0.f, 0.f, 0.f, 0.f);
    if (row < NN) v = *(const float4*)(h + (size_t)row * D + q * 4);
    *(float4*)&lds[r][q * 4] = v;
  }
  __syncthreads();

  int wv = tid >> 6, lane = tid & 63;
  int rbase = wv * 8;
  bool act = lane < NCLS;
  float accS[8], accZ[8];
#pragma unroll
  for (int r = 0; r < 8; ++r) { accS[r] = 0.f; accZ[r] = 0.f; }

  // 32 chunks of 4 k-rows; cw[0..3]=self rows, cw[4..7]=neigh rows.
  float cw[8], nw[8];
#pragma unroll
  for (int j = 0; j < 4; ++j) {
    cw[j]     = act ? ws[j * NCLS + lane] : 0.f;
    cw[4 + j] = act ? wn[j * NCLS + lane] : 0.f;
  }
#pragma unroll 2
  for (int c = 0; c < 32; ++c) {
    int cn = (c + 1 < 32) ? c + 1 : 31;
    // batch-load current chunk's 8 rows
    float4 hv[8];
#pragma unroll
    for (int r = 0; r < 8; ++r) hv[r] = *(const float4*)&lds[rbase + r][c * 4];
#pragma unroll
    for (int j = 0; j < 4; ++j) {
      nw[j]     = act ? ws[(cn * 4 + j) * NCLS + lane] : 0.f;
      nw[4 + j] = act ? wn[(cn * 4 + j) * NCLS + lane] : 0.f;
    }
#pragma unroll
    for (int r = 0; r < 8; ++r) {
      accS[r] = fmaf(hv[r].x, cw[0], accS[r]);
      accZ[r] = fmaf(hv[r].x, cw[4], accZ[r]);
      accS[r] = fmaf(hv[r].y, cw[1], accS[r]);
      accZ[r] = fmaf(hv[r].y, cw[5], accZ[r]);
      accS[r] = fmaf(hv[r].z, cw[2], accS[r]);
      accZ[r] = fmaf(hv[r].z, cw[6], accZ[r]);
      accS[r] = fmaf(hv[r].w, cw[3], accS[r]);
      accZ[r] = fmaf(hv[r].w, cw[7], accZ[r]);
    }
#pragma unroll
    for (int j = 0; j < 8; ++j) cw[j] = nw[j];
  }

  float bj = act ? b[lane] : 0.f;
#pragma unroll
  for (int r = 0; r < 8; ++r) {
    int row = row0 + rbase + r;
    if (row < NN) {
      // all 64 lanes write z2 so the pad cols are ZERO (gather reads them)
      z2[(size_t)row * ZPAD + lane] = act ? accZ[r] : 0.f;
      s2p[(size_t)row * ZPAD + lane] = accS[r] + bj;  // pad lanes never read
    }
  }
}

// ---------------- layer 2 final: out = s2p + mean_neigh(z2), XCD-sliced ----------------
// slice = blockIdx.x & 7 covers 8 cols; per-XCD z2 slice = 1.6 MB -> L2-resident.
__global__ __launch_bounds__(256) void k_agg2(const float* __restrict__ z2,
                                              const float* __restrict__ s2p,
                                              const int* __restrict__ indptr,
                                              const int* __restrict__ esrc,
                                              float* __restrict__ out) {
  int bid = blockIdx.x;
  int slice = bid & 7;
  int chunk = bid >> 3;
  int tid = threadIdx.x;
  int node = chunk * 32 + (tid >> 3);
  if (node >= NN) return;
  int col = (slice << 3) | (tid & 7);
  const float* zc = z2 + col;
  int beg = indptr[node], end = indptr[node + 1];
  float a = 0.f;
  int e = beg;
  for (; e + 7 < end; e += 8) {
    int idx[8];
#pragma unroll
    for (int j = 0; j < 8; ++j) idx[j] = esrc[e + j];
    float v[8];
#pragma unroll
    for (int j = 0; j < 8; ++j) v[j] = zc[(size_t)idx[j] * ZPAD];
#pragma unroll
    for (int j = 0; j < 8; ++j) a += v[j];
  }
  for (; e < end; ++e) a += zc[(size_t)esrc[e] * ZPAD];
  float inv = 1.0f / fmaxf((float)(end - beg), 1.0f);
  if (col < NCLS)
    out[(size_t)node * NCLS + col] = s2p[(size_t)node * ZPAD + col] + a * inv;
}

// ---------------- launch ----------------
extern "C" void kernel_launch(void* const* d_in, const int* in_sizes, int n_in,
                              void* d_out, int out_size, void* d_ws, size_t ws_size,
                              hipStream_t stream) {
  (void)in_sizes; (void)n_in; (void)out_size; (void)ws_size;
  const float* x       = (const float*)d_in[0];
  const int*   src     = (const int*)d_in[1];
  const int*   dst     = (const int*)d_in[2];
  const float* w_self0 = (const float*)d_in[3];
  const float* w_nei0  = (const float*)d_in[4];
  const float* b0      = (const float*)d_in[5];
  const float* g0      = (const float*)d_in[6];
  const float* be0     = (const float*)d_in[7];
  const float* w_self1 = (const float*)d_in[8];
  const float* w_nei1  = (const float*)d_in[9];
  const float* b1      = (const float*)d_in[10];
  const float* g1      = (const float*)d_in[11];
  const float* be1     = (const float*)d_in[12];
  const float* w_self2 = (const float*)d_in[13];
  const float* w_nei2  = (const float*)d_in[14];
  const float* b2      = (const float*)d_in[15];
  float* outp = (float*)d_out;

  char* ws = (char*)d_ws;
  size_t off = 0;
  auto alloc = [&](size_t bytes) -> void* {
    off = (off + 255) & ~(size_t)255;
    void* p = ws + off;
    off += bytes;
    return p;
  };
  int*   counts = (int*)alloc(NN * sizeof(int));
  int*   indptr = (int*)alloc((NN + 1) * sizeof(int));
  int*   cursor = (int*)alloc(NN * sizeof(int));
  int*   bsum   = (int*)alloc(256 * sizeof(int));
  int*   esrc   = (int*)alloc(NE * sizeof(int));
  float* hn     = (float*)alloc((size_t)NN * D * sizeof(float));  // also z2 (layer 2)
  float* h1     = (float*)alloc((size_t)NN * D * sizeof(float));  // also s2p (layer 2)
  float* h2     = (float*)alloc((size_t)NN * D * sizeof(float));
  float* z2  = hn;  // 12.8 MB into 25.6 MB slot
  float* s2p = h1;  // h1 dead once h2 exists

  const int nbScan = (NN + 255) / 256;  // 196

  // CSR build
  hipMemsetAsync(counts, 0, NN * sizeof(int), stream);
  k_count<<<(NE + 255) / 256, 256, 0, stream>>>(dst, counts);
  k_scan1<<<nbScan, 256, 0, stream>>>(counts, indptr, bsum);
  k_scan2<<<1, 256, 0, stream>>>(bsum, nbScan);
  k_scan3<<<nbScan, 256, 0, stream>>>(indptr, bsum, cursor);
  k_scatter<<<(NE + 255) / 256, 256, 0, stream>>>(src, dst, cursor, esrc);

  const int aggBlocks  = ((NN + 15) / 16) * 8;   // 25000 (16 nodes/block, 8 slices)
  const int agg2Blocks = ((NN + 31) / 32) * 8;   // 12504 (32 nodes/block, 8 slices)
  const int gemmBlocks = (NN + 31) / 32;         // 1563

  // layer 0
  k_agg<<<aggBlocks, 256, 0, stream>>>(x, indptr, esrc, hn);
  k_gemm_ln<<<gemmBlocks, 256, 0, stream>>>(x, hn, w_self0, w_nei0, b0, g0, be0, h1);
  // layer 1
  k_agg<<<aggBlocks, 256, 0, stream>>>(h1, indptr, esrc, hn);
  k_gemm_ln<<<gemmBlocks, 256, 0, stream>>>(h1, hn, w_self1, w_nei1, b1, g1, be1, h2);
  // layer 2: project first (agg commutes with the linear map), then 64-wide agg
  k_gemm_proj2<<<gemmBlocks, 256, 0, stream>>>(h2, w_self2, w_nei2, b2, s2p, z2);
  k_agg2<<<agg2Blocks, 256, 0, stream>>>(z2, s2p, indptr, esrc, outp);
}

// Round 9
// 600.451 us; speedup vs baseline: 2.0116x; 2.0116x over previous
//
#include <hip/hip_runtime.h>

#define NN 50000
#define NE 800000
#define D 128
#define NCLS 47
#define ZPAD 64   // padded width for projected layer-2 features
#define LN_EPS 1e-5f

// ---------------- CSR build ----------------
__global__ void k_count(const int* __restrict__ dst, int* __restrict__ counts) {
  int i = blockIdx.x * blockDim.x + threadIdx.x;
  if (i < NE) atomicAdd(&counts[dst[i]], 1);
}

__global__ void k_scan1(const int* __restrict__ counts, int* __restrict__ excl,
                        int* __restrict__ bsum) {
  __shared__ int tmp[256];
  int t = threadIdx.x, i = blockIdx.x * 256 + t;
  int v = (i < NN) ? counts[i] : 0;
  tmp[t] = v;
  __syncthreads();
  for (int off = 1; off < 256; off <<= 1) {
    int u = (t >= off) ? tmp[t - off] : 0;
    __syncthreads();
    tmp[t] += u;
    __syncthreads();
  }
  if (i < NN) excl[i] = tmp[t] - v;
  if (t == 255) bsum[blockIdx.x] = tmp[255];
}

__global__ void k_scan2(int* __restrict__ bsum, int nb) {
  __shared__ int tmp[256];
  int t = threadIdx.x;
  int v = (t < nb) ? bsum[t] : 0;
  tmp[t] = v;
  __syncthreads();
  for (int off = 1; off < 256; off <<= 1) {
    int u = (t >= off) ? tmp[t - off] : 0;
    __syncthreads();
    tmp[t] += u;
    __syncthreads();
  }
  if (t < nb) bsum[t] = tmp[t] - v;
}

__global__ void k_scan3(int* __restrict__ indptr, const int* __restrict__ bsum,
                        int* __restrict__ cursor) {
  int i = blockIdx.x * 256 + threadIdx.x;
  if (i < NN) {
    int v = indptr[i] + bsum[i >> 8];
    indptr[i] = v;
    cursor[i] = v;
  }
  if (i == 0) indptr[NN] = NE;
}

__global__ void k_scatter(const int* __restrict__ src, const int* __restrict__ dst,
                          int* __restrict__ cursor, int* __restrict__ esrc) {
  int i = blockIdx.x * blockDim.x + threadIdx.x;
  if (i < NE) {
    int d = dst[i];
    int pos = atomicAdd(&cursor[d], 1);
    esrc[pos] = src[i];
  }
}

// ---------------- mean aggregation (128-wide): one wave per node, 16 chains ----------------
__global__ __launch_bounds__(256) void k_agg(const float* __restrict__ feat,
                                             const int* __restrict__ indptr,
                                             const int* __restrict__ esrc,
                                             float* __restrict__ out) {
  int w = (blockIdx.x * 256 + threadIdx.x) >> 6;
  int lane = threadIdx.x & 63;
  if (w >= NN) return;
  int beg = indptr[w], end = indptr[w + 1];
  float a0 = 0.f, a1 = 0.f;
  int e = beg;
  for (; e + 15 < end; e += 16) {  // 16 independent gather chains in flight
    int idx[16];
#pragma unroll
    for (int j = 0; j < 16; ++j) idx[j] = esrc[e + j];
    float2 v[16];
#pragma unroll
    for (int j = 0; j < 16; ++j)
      v[j] = *(const float2*)(feat + (size_t)idx[j] * D + lane * 2);
#pragma unroll
    for (int j = 0; j < 16; ++j) { a0 += v[j].x; a1 += v[j].y; }
  }
  for (; e + 3 < end; e += 4) {
    int i0 = esrc[e], i1 = esrc[e + 1], i2 = esrc[e + 2], i3 = esrc[e + 3];
    float2 v0 = *(const float2*)(feat + (size_t)i0 * D + lane * 2);
    float2 v1 = *(const float2*)(feat + (size_t)i1 * D + lane * 2);
    float2 v2 = *(const float2*)(feat + (size_t)i2 * D + lane * 2);
    float2 v3 = *(const float2*)(feat + (size_t)i3 * D + lane * 2);
    a0 += v0.x + v1.x + v2.x + v3.x;
    a1 += v0.y + v1.y + v2.y + v3.y;
  }
  for (; e < end; ++e) {
    float2 v0 = *(const float2*)(feat + (size_t)esrc[e] * D + lane * 2);
    a0 += v0.x;
    a1 += v0.y;
  }
  float inv = 1.0f / fmaxf((float)(end - beg), 1.0f);
  float2 o;
  o.x = a0 * inv;
  o.y = a1 * inv;
  *(float2*)(out + (size_t)w * D + lane * 2) = o;
}

// ---------------- fused dual-GEMM + LN + ReLU (hidden layers) ----------------
// 32 rows/block (32 KB LDS, 5 blocks/CU = 160 KB), 256 thr (4 waves), wave
// handles 8 rows, lane j owns cols j and j+64. Per chunk: batch all 8 rows'
// ds_read_b128 first (8 outstanding), then 64 FMAs. Weights pipelined 1 ahead.
// NOTE: (256,5) -> VGPR cap ~102, kernel uses ~52 -> no spill.
__global__ __launch_bounds__(256, 5) void k_gemm_ln(
    const float* __restrict__ h, const float* __restrict__ hn,
    const float* __restrict__ ws, const float* __restrict__ wn,
    const float* __restrict__ b, const float* __restrict__ g,
    const float* __restrict__ be, float* __restrict__ out) {
  __shared__ float lds[32][256];  // cols [0,128)=h, [128,256)=hn (32 KB)
  int tid = threadIdx.x;
  int row0 = blockIdx.x * 32;
  for (int i = tid; i < 32 * 64; i += 256) {  // float4 granules, 64 per row
    int r = i >> 6, q = i & 63;
    int row = row0 + r;
    float4 v = make_float4(0.f, 0.f, 0.f, 0.f);
    if (row < NN) {
      const float* p = (q < 32) ? (h + (size_t)row * D + q * 4)
                                : (hn + (size_t)row * D + (q - 32) * 4);
      v = *(const float4*)p;
    }
    *(float4*)&lds[r][q * 4] = v;
  }
  __syncthreads();

  int wv = tid >> 6, lane = tid & 63;
  int rbase = wv * 8;
  float acc0[8], acc1[8];
#pragma unroll
  for (int r = 0; r < 8; ++r) { acc0[r] = 0.f; acc1[r] = 0.f; }

  // 64 chunks of 4 k-rows: c in [0,32) -> ws, [32,64) -> wn; lds col = c*4.
  float cw[8], nw[8];
#pragma unroll
  for (int j = 0; j < 4; ++j) {  // preload chunk 0 (self rows 0..3)
    cw[2 * j]     = ws[j * 128 + lane];
    cw[2 * j + 1] = ws[j * 128 + lane + 64];
  }
#pragma unroll 2
  for (int c = 0; c < 64; ++c) {
    int cn = (c + 1 < 64) ? c + 1 : 63;  // last iter: harmless reload
    const float* np = ((cn & 32) ? wn : ws) + (cn & 31) * 512;
    // batch-load current chunk's 8 rows -> 8 ds_read_b128 in flight
    float4 hv[8];
#pragma unroll
    for (int r = 0; r < 8; ++r) hv[r] = *(const float4*)&lds[rbase + r][c * 4];
    // prefetch next chunk's weights (8 global loads in flight over the FMAs)
#pragma unroll
    for (int j = 0; j < 4; ++j) {
      nw[2 * j]     = np[j * 128 + lane];
      nw[2 * j + 1] = np[j * 128 + lane + 64];
    }
#pragma unroll
    for (int r = 0; r < 8; ++r) {
      acc0[r] = fmaf(hv[r].x, cw[0], acc0[r]);
      acc1[r] = fmaf(hv[r].x, cw[1], acc1[r]);
      acc0[r] = fmaf(hv[r].y, cw[2], acc0[r]);
      acc1[r] = fmaf(hv[r].y, cw[3], acc1[r]);
      acc0[r] = fmaf(hv[r].z, cw[4], acc0[r]);
      acc1[r] = fmaf(hv[r].z, cw[5], acc1[r]);
      acc0[r] = fmaf(hv[r].w, cw[6], acc0[r]);
      acc1[r] = fmaf(hv[r].w, cw[7], acc1[r]);
    }
#pragma unroll
    for (int j = 0; j < 8; ++j) cw[j] = nw[j];
  }

  float bj0 = b[lane], bj1 = b[lane + 64];
  float gj0 = g[lane], gj1 = g[lane + 64];
  float ej0 = be[lane], ej1 = be[lane + 64];
#pragma unroll
  for (int r = 0; r < 8; ++r) {
    float v0 = acc0[r] + bj0, v1 = acc1[r] + bj1;
    float s = v0 + v1, q2 = v0 * v0 + v1 * v1;
#pragma unroll
    for (int off = 1; off < 64; off <<= 1) {
      s += __shfl_xor(s, off, 64);
      q2 += __shfl_xor(q2, off, 64);
    }
    float mu = s * (1.0f / 128.0f);
    float var = q2 * (1.0f / 128.0f) - mu * mu;
    float rs = rsqrtf(var + LN_EPS);
    float o0 = fmaxf((v0 - mu) * rs * gj0 + ej0, 0.f);
    float o1 = fmaxf((v1 - mu) * rs * gj1 + ej1, 0.f);
    int row = row0 + rbase + r;
    if (row < NN) {
      out[(size_t)row * D + lane] = o0;
      out[(size_t)row * D + lane + 64] = o1;
    }
  }
}

// ---------------- layer 2: project h2 through BOTH weight matrices ----------------
// s2p[row][j] = (h2 @ w_self2)[row][j] + b2[j]   (j < 47)
// z2 [row][j] = (h2 @ w_neigh2)[row][j]          (j < 47; cols 47..63 zeroed)
// (256,4): VGPR cap 128 -- hv[8]+cw+nw+accs fit (~52 regs), NO spill.
__global__ __launch_bounds__(256, 4) void k_gemm_proj2(
    const float* __restrict__ h, const float* __restrict__ ws,
    const float* __restrict__ wn, const float* __restrict__ b,
    float* __restrict__ s2p, float* __restrict__ z2) {
  __shared__ float lds[32][128];  // 16 KB
  int tid = threadIdx.x;
  int row0 = blockIdx.x * 32;
  for (int i = tid; i < 32 * 32; i += 256) {  // float4 granules, 32 per row
    int r = i >> 5, q = i & 31;
    int row = row0 + r;
    float4 v = make_float4(0.f, 0.f, 0.f, 0.f);
    if (row < NN) v = *(const float4*)(h + (size_t)row * D + q * 4);
    *(float4*)&lds[r][q * 4] = v;
  }
  __syncthreads();

  int wv = tid >> 6, lane = tid & 63;
  int rbase = wv * 8;
  bool act = lane < NCLS;
  float accS[8], accZ[8];
#pragma unroll
  for (int r = 0; r < 8; ++r) { accS[r] = 0.f; accZ[r] = 0.f; }

  // 32 chunks of 4 k-rows; cw[0..3]=self rows, cw[4..7]=neigh rows.
  float cw[8], nw[8];
#pragma unroll
  for (int j = 0; j < 4; ++j) {
    cw[j]     = act ? ws[j * NCLS + lane] : 0.f;
    cw[4 + j] = act ? wn[j * NCLS + lane] : 0.f;
  }
#pragma unroll 2
  for (int c = 0; c < 32; ++c) {
    int cn = (c + 1 < 32) ? c + 1 : 31;
    // batch-load current chunk's 8 rows
    float4 hv[8];
#pragma unroll
    for (int r = 0; r < 8; ++r) hv[r] = *(const float4*)&lds[rbase + r][c * 4];
#pragma unroll
    for (int j = 0; j < 4; ++j) {
      nw[j]     = act ? ws[(cn * 4 + j) * NCLS + lane] : 0.f;
      nw[4 + j] = act ? wn[(cn * 4 + j) * NCLS + lane] : 0.f;
    }
#pragma unroll
    for (int r = 0; r < 8; ++r) {
      accS[r] = fmaf(hv[r].x, cw[0], accS[r]);
      accZ[r] = fmaf(hv[r].x, cw[4], accZ[r]);
      accS[r] = fmaf(hv[r].y, cw[1], accS[r]);
      accZ[r] = fmaf(hv[r].y, cw[5], accZ[r]);
      accS[r] = fmaf(hv[r].z, cw[2], accS[r]);
      accZ[r] = fmaf(hv[r].z, cw[6], accZ[r]);
      accS[r] = fmaf(hv[r].w, cw[3], accS[r]);
      accZ[r] = fmaf(hv[r].w, cw[7], accZ[r]);
    }
#pragma unroll
    for (int j = 0; j < 8; ++j) cw[j] = nw[j];
  }

  float bj = act ? b[lane] : 0.f;
#pragma unroll
  for (int r = 0; r < 8; ++r) {
    int row = row0 + rbase + r;
    if (row < NN) {
      // all 64 lanes write z2 so the pad cols are ZERO (gather reads them)
      z2[(size_t)row * ZPAD + lane] = act ? accZ[r] : 0.f;
      s2p[(size_t)row * ZPAD + lane] = accS[r] + bj;  // pad lanes never read
    }
  }
}

// ---------------- layer 2 final: out = s2p + mean_neigh(z2) ----------------
__global__ __launch_bounds__(256) void k_agg2(const float* __restrict__ z2,
                                              const float* __restrict__ s2p,
                                              const int* __restrict__ indptr,
                                              const int* __restrict__ esrc,
                                              float* __restrict__ out) {
  int w = (blockIdx.x * 256 + threadIdx.x) >> 6;
  int lane = threadIdx.x & 63;
  if (w >= NN) return;
  int beg = indptr[w], end = indptr[w + 1];
  float a = 0.f;
  int e = beg;
  for (; e + 15 < end; e += 16) {
    int idx[16];
#pragma unroll
    for (int j = 0; j < 16; ++j) idx[j] = esrc[e + j];
    float v[16];
#pragma unroll
    for (int j = 0; j < 16; ++j) v[j] = z2[(size_t)idx[j] * ZPAD + lane];
#pragma unroll
    for (int j = 0; j < 16; ++j) a += v[j];
  }
  for (; e + 3 < end; e += 4) {
    int i0 = esrc[e], i1 = esrc[e + 1], i2 = esrc[e + 2], i3 = esrc[e + 3];
    a += z2[(size_t)i0 * ZPAD + lane] + z2[(size_t)i1 * ZPAD + lane] +
         z2[(size_t)i2 * ZPAD + lane] + z2[(size_t)i3 * ZPAD + lane];
  }
  for (; e < end; ++e) a += z2[(size_t)esrc[e] * ZPAD + lane];
  float inv = 1.0f / fmaxf((float)(end - beg), 1.0f);
  if (lane < NCLS)
    out[(size_t)w * NCLS + lane] = s2p[(size_t)w * ZPAD + lane] + a * inv;
}

// ---------------- launch ----------------
extern "C" void kernel_launch(void* const* d_in, const int* in_sizes, int n_in,
                              void* d_out, int out_size, void* d_ws, size_t ws_size,
                              hipStream_t stream) {
  (void)in_sizes; (void)n_in; (void)out_size; (void)ws_size;
  const float* x       = (const float*)d_in[0];
  const int*   src     = (const int*)d_in[1];
  const int*   dst     = (const int*)d_in[2];
  const float* w_self0 = (const float*)d_in[3];
  const float* w_nei0  = (const float*)d_in[4];
  const float* b0      = (const float*)d_in[5];
  const float* g0      = (const float*)d_in[6];
  const float* be0     = (const float*)d_in[7];
  const float* w_self1 = (const float*)d_in[8];
  const float* w_nei1  = (const float*)d_in[9];
  const float* b1      = (const float*)d_in[10];
  const float* g1      = (const float*)d_in[11];
  const float* be1     = (const float*)d_in[12];
  const float* w_self2 = (const float*)d_in[13];
  const float* w_nei2  = (const float*)d_in[14];
  const float* b2      = (const float*)d_in[15];
  float* outp = (float*)d_out;

  char* ws = (char*)d_ws;
  size_t off = 0;
  auto alloc = [&](size_t bytes) -> void* {
    off = (off + 255) & ~(size_t)255;
    void* p = ws + off;
    off += bytes;
    return p;
  };
  int*   counts = (int*)alloc(NN * sizeof(int));
  int*   indptr = (int*)alloc((NN + 1) * sizeof(int));
  int*   cursor = (int*)alloc(NN * sizeof(int));
  int*   bsum   = (int*)alloc(256 * sizeof(int));
  int*   esrc   = (int*)alloc(NE * sizeof(int));
  float* hn     = (float*)alloc((size_t)NN * D * sizeof(float));  // also z2 (layer 2)
  float* h1     = (float*)alloc((size_t)NN * D * sizeof(float));  // also s2p (layer 2)
  float* h2     = (float*)alloc((size_t)NN * D * sizeof(float));
  float* z2  = hn;  // 12.8 MB into 25.6 MB slot
  float* s2p = h1;  // h1 dead once h2 exists

  const int nbScan = (NN + 255) / 256;  // 196

  // CSR build
  hipMemsetAsync(counts, 0, NN * sizeof(int), stream);
  k_count<<<(NE + 255) / 256, 256, 0, stream>>>(dst, counts);
  k_scan1<<<nbScan, 256, 0, stream>>>(counts, indptr, bsum);
  k_scan2<<<1, 256, 0, stream>>>(bsum, nbScan);
  k_scan3<<<nbScan, 256, 0, stream>>>(indptr, bsum, cursor);
  k_scatter<<<(NE + 255) / 256, 256, 0, stream>>>(src, dst, cursor, esrc);

  const int aggBlocks  = (NN * 64) / 256;   // 12500
  const int gemmBlocks = (NN + 31) / 32;    // 1563

  // layer 0
  k_agg<<<aggBlocks, 256, 0, stream>>>(x, indptr, esrc, hn);
  k_gemm_ln<<<gemmBlocks, 256, 0, stream>>>(x, hn, w_self0, w_nei0, b0, g0, be0, h1);
  // layer 1
  k_agg<<<aggBlocks, 256, 0, stream>>>(h1, indptr, esrc, hn);
  k_gemm_ln<<<gemmBlocks, 256, 0, stream>>>(h1, hn, w_self1, w_nei1, b1, g1, be1, h2);
  // layer 2: project first (agg commutes with the linear map), then 64-wide agg
  k_gemm_proj2<<<gemmBlocks, 256, 0, stream>>>(h2, w_self2, w_nei2, b2, s2p, z2);
  k_agg2<<<aggBlocks, 256, 0, stream>>>(z2, s2p, indptr, esrc, outp);
}

// Round 10
// 490.790 us; speedup vs baseline: 2.4611x; 1.2234x over previous
//
#include <hip/hip_runtime.h>

#define NN 50000
#define NE 800000
#define D 128
#define NCLS 47
#define ZPAD 64   // padded width for projected layer-2 features
#define LN_EPS 1e-5f

// ---------------- CSR build ----------------
__global__ void k_count(const int* __restrict__ dst, int* __restrict__ counts) {
  int i = blockIdx.x * blockDim.x + threadIdx.x;
  if (i < NE) atomicAdd(&counts[dst[i]], 1);
}

__global__ void k_scan1(const int* __restrict__ counts, int* __restrict__ excl,
                        int* __restrict__ bsum) {
  __shared__ int tmp[256];
  int t = threadIdx.x, i = blockIdx.x * 256 + t;
  int v = (i < NN) ? counts[i] : 0;
  tmp[t] = v;
  __syncthreads();
  for (int off = 1; off < 256; off <<= 1) {
    int u = (t >= off) ? tmp[t - off] : 0;
    __syncthreads();
    tmp[t] += u;
    __syncthreads();
  }
  if (i < NN) excl[i] = tmp[t] - v;
  if (t == 255) bsum[blockIdx.x] = tmp[255];
}

__global__ void k_scan2(int* __restrict__ bsum, int nb) {
  __shared__ int tmp[256];
  int t = threadIdx.x;
  int v = (t < nb) ? bsum[t] : 0;
  tmp[t] = v;
  __syncthreads();
  for (int off = 1; off < 256; off <<= 1) {
    int u = (t >= off) ? tmp[t - off] : 0;
    __syncthreads();
    tmp[t] += u;
    __syncthreads();
  }
  if (t < nb) bsum[t] = tmp[t] - v;
}

__global__ void k_scan3(int* __restrict__ indptr, const int* __restrict__ bsum,
                        int* __restrict__ cursor) {
  int i = blockIdx.x * 256 + threadIdx.x;
  if (i < NN) {
    int v = indptr[i] + bsum[i >> 8];
    indptr[i] = v;
    cursor[i] = v;
  }
  if (i == 0) indptr[NN] = NE;
}

__global__ void k_scatter(const int* __restrict__ src, const int* __restrict__ dst,
                          int* __restrict__ cursor, int* __restrict__ esrc) {
  int i = blockIdx.x * blockDim.x + threadIdx.x;
  if (i < NE) {
    int d = dst[i];
    int pos = atomicAdd(&cursor[d], 1);
    esrc[pos] = src[i];
  }
}

// ---------------- mean aggregation (128-wide): one wave per node, 16 chains ----------------
__global__ __launch_bounds__(256) void k_agg(const float* __restrict__ feat,
                                             const int* __restrict__ indptr,
                                             const int* __restrict__ esrc,
                                             float* __restrict__ out) {
  int w = (blockIdx.x * 256 + threadIdx.x) >> 6;
  int lane = threadIdx.x & 63;
  if (w >= NN) return;
  int beg = indptr[w], end = indptr[w + 1];
  float a0 = 0.f, a1 = 0.f;
  int e = beg;
  for (; e + 15 < end; e += 16) {  // 16 independent gather chains in flight
    int idx[16];
#pragma unroll
    for (int j = 0; j < 16; ++j) idx[j] = esrc[e + j];
    float2 v[16];
#pragma unroll
    for (int j = 0; j < 16; ++j)
      v[j] = *(const float2*)(feat + (size_t)idx[j] * D + lane * 2);
#pragma unroll
    for (int j = 0; j < 16; ++j) { a0 += v[j].x; a1 += v[j].y; }
  }
  for (; e + 3 < end; e += 4) {
    int i0 = esrc[e], i1 = esrc[e + 1], i2 = esrc[e + 2], i3 = esrc[e + 3];
    float2 v0 = *(const float2*)(feat + (size_t)i0 * D + lane * 2);
    float2 v1 = *(const float2*)(feat + (size_t)i1 * D + lane * 2);
    float2 v2 = *(const float2*)(feat + (size_t)i2 * D + lane * 2);
    float2 v3 = *(const float2*)(feat + (size_t)i3 * D + lane * 2);
    a0 += v0.x + v1.x + v2.x + v3.x;
    a1 += v0.y + v1.y + v2.y + v3.y;
  }
  for (; e < end; ++e) {
    float2 v0 = *(const float2*)(feat + (size_t)esrc[e] * D + lane * 2);
    a0 += v0.x;
    a1 += v0.y;
  }
  float inv = 1.0f / fmaxf((float)(end - beg), 1.0f);
  float2 o;
  o.x = a0 * inv;
  o.y = a1 * inv;
  *(float2*)(out + (size_t)w * D + lane * 2) = o;
}

// ---------------- fused dual-GEMM + LN + ReLU (hidden layers) ----------------
// 32 rows/block (32 KB LDS), 256 thr (4 waves), wave handles 8 rows, lane j
// owns cols j and j+64. Per chunk: batch all 8 rows' ds_read_b128 first
// (8 outstanding), then 64 FMAs. Weights pipelined 1 chunk ahead.
// (256,4): VGPR cap 128; the hv[8]+cw+nw+acc working set (~64 live) NEEDS
// this headroom — (256,5) capped regs at 48, serialized the loads and
// spilled (measured R9: 129 µs vs 72.9 µs). DO NOT raise the bound.
__global__ __launch_bounds__(256, 4) void k_gemm_ln(
    const float* __restrict__ h, const float* __restrict__ hn,
    const float* __restrict__ ws, const float* __restrict__ wn,
    const float* __restrict__ b, const float* __restrict__ g,
    const float* __restrict__ be, float* __restrict__ out) {
  __shared__ float lds[32][256];  // cols [0,128)=h, [128,256)=hn (32 KB)
  int tid = threadIdx.x;
  int row0 = blockIdx.x * 32;
  for (int i = tid; i < 32 * 64; i += 256) {  // float4 granules, 64 per row
    int r = i >> 6, q = i & 63;
    int row = row0 + r;
    float4 v = make_float4(0.f, 0.f, 0.f, 0.f);
    if (row < NN) {
      const float* p = (q < 32) ? (h + (size_t)row * D + q * 4)
                                : (hn + (size_t)row * D + (q - 32) * 4);
      v = *(const float4*)p;
    }
    *(float4*)&lds[r][q * 4] = v;
  }
  __syncthreads();

  int wv = tid >> 6, lane = tid & 63;
  int rbase = wv * 8;
  float acc0[8], acc1[8];
#pragma unroll
  for (int r = 0; r < 8; ++r) { acc0[r] = 0.f; acc1[r] = 0.f; }

  // 64 chunks of 4 k-rows: c in [0,32) -> ws, [32,64) -> wn; lds col = c*4.
  float cw[8], nw[8];
#pragma unroll
  for (int j = 0; j < 4; ++j) {  // preload chunk 0 (self rows 0..3)
    cw[2 * j]     = ws[j * 128 + lane];
    cw[2 * j + 1] = ws[j * 128 + lane + 64];
  }
#pragma unroll 2
  for (int c = 0; c < 64; ++c) {
    int cn = (c + 1 < 64) ? c + 1 : 63;  // last iter: harmless reload
    const float* np = ((cn & 32) ? wn : ws) + (cn & 31) * 512;
    // batch-load current chunk's 8 rows -> 8 ds_read_b128 in flight
    float4 hv[8];
#pragma unroll
    for (int r = 0; r < 8; ++r) hv[r] = *(const float4*)&lds[rbase + r][c * 4];
    // prefetch next chunk's weights (8 global loads in flight over the FMAs)
#pragma unroll
    for (int j = 0; j < 4; ++j) {
      nw[2 * j]     = np[j * 128 + lane];
      nw[2 * j + 1] = np[j * 128 + lane + 64];
    }
#pragma unroll
    for (int r = 0; r < 8; ++r) {
      acc0[r] = fmaf(hv[r].x, cw[0], acc0[r]);
      acc1[r] = fmaf(hv[r].x, cw[1], acc1[r]);
      acc0[r] = fmaf(hv[r].y, cw[2], acc0[r]);
      acc1[r] = fmaf(hv[r].y, cw[3], acc1[r]);
      acc0[r] = fmaf(hv[r].z, cw[4], acc0[r]);
      acc1[r] = fmaf(hv[r].z, cw[5], acc1[r]);
      acc0[r] = fmaf(hv[r].w, cw[6], acc0[r]);
      acc1[r] = fmaf(hv[r].w, cw[7], acc1[r]);
    }
#pragma unroll
    for (int j = 0; j < 8; ++j) cw[j] = nw[j];
  }

  float bj0 = b[lane], bj1 = b[lane + 64];
  float gj0 = g[lane], gj1 = g[lane + 64];
  float ej0 = be[lane], ej1 = be[lane + 64];
#pragma unroll
  for (int r = 0; r < 8; ++r) {
    float v0 = acc0[r] + bj0, v1 = acc1[r] + bj1;
    float s = v0 + v1, q2 = v0 * v0 + v1 * v1;
#pragma unroll
    for (int off = 1; off < 64; off <<= 1) {
      s += __shfl_xor(s, off, 64);
      q2 += __shfl_xor(q2, off, 64);
    }
    float mu = s * (1.0f / 128.0f);
    float var = q2 * (1.0f / 128.0f) - mu * mu;
    float rs = rsqrtf(var + LN_EPS);
    float o0 = fmaxf((v0 - mu) * rs * gj0 + ej0, 0.f);
    float o1 = fmaxf((v1 - mu) * rs * gj1 + ej1, 0.f);
    int row = row0 + rbase + r;
    if (row < NN) {
      out[(size_t)row * D + lane] = o0;
      out[(size_t)row * D + lane + 64] = o1;
    }
  }
}

// ---------------- layer 2: project h2 through BOTH weight matrices ----------------
// s2p[row][j] = (h2 @ w_self2)[row][j] + b2[j]   (j < 47)
// z2 [row][j] = (h2 @ w_neigh2)[row][j]          (j < 47; cols 47..63 zeroed)
// (256,4): VGPR cap 128 -- hv[8]+cw+nw+accs fit, NO spill (see R8 disaster at (256,8)).
__global__ __launch_bounds__(256, 4) void k_gemm_proj2(
    const float* __restrict__ h, const float* __restrict__ ws,
    const float* __restrict__ wn, const float* __restrict__ b,
    float* __restrict__ s2p, float* __restrict__ z2) {
  __shared__ float lds[32][128];  // 16 KB
  int tid = threadIdx.x;
  int row0 = blockIdx.x * 32;
  for (int i = tid; i < 32 * 32; i += 256) {  // float4 granules, 32 per row
    int r = i >> 5, q = i & 31;
    int row = row0 + r;
    float4 v = make_float4(0.f, 0.f, 0.f, 0.f);
    if (row < NN) v = *(const float4*)(h + (size_t)row * D + q * 4);
    *(float4*)&lds[r][q * 4] = v;
  }
  __syncthreads();

  int wv = tid >> 6, lane = tid & 63;
  int rbase = wv * 8;
  bool act = lane < NCLS;
  float accS[8], accZ[8];
#pragma unroll
  for (int r = 0; r < 8; ++r) { accS[r] = 0.f; accZ[r] = 0.f; }

  // 32 chunks of 4 k-rows; cw[0..3]=self rows, cw[4..7]=neigh rows.
  float cw[8], nw[8];
#pragma unroll
  for (int j = 0; j < 4; ++j) {
    cw[j]     = act ? ws[j * NCLS + lane] : 0.f;
    cw[4 + j] = act ? wn[j * NCLS + lane] : 0.f;
  }
#pragma unroll 2
  for (int c = 0; c < 32; ++c) {
    int cn = (c + 1 < 32) ? c + 1 : 31;
    // batch-load current chunk's 8 rows
    float4 hv[8];
#pragma unroll
    for (int r = 0; r < 8; ++r) hv[r] = *(const float4*)&lds[rbase + r][c * 4];
#pragma unroll
    for (int j = 0; j < 4; ++j) {
      nw[j]     = act ? ws[(cn * 4 + j) * NCLS + lane] : 0.f;
      nw[4 + j] = act ? wn[(cn * 4 + j) * NCLS + lane] : 0.f;
    }
#pragma unroll
    for (int r = 0; r < 8; ++r) {
      accS[r] = fmaf(hv[r].x, cw[0], accS[r]);
      accZ[r] = fmaf(hv[r].x, cw[4], accZ[r]);
      accS[r] = fmaf(hv[r].y, cw[1], accS[r]);
      accZ[r] = fmaf(hv[r].y, cw[5], accZ[r]);
      accS[r] = fmaf(hv[r].z, cw[2], accS[r]);
      accZ[r] = fmaf(hv[r].z, cw[6], accZ[r]);
      accS[r] = fmaf(hv[r].w, cw[3], accS[r]);
      accZ[r] = fmaf(hv[r].w, cw[7], accZ[r]);
    }
#pragma unroll
    for (int j = 0; j < 8; ++j) cw[j] = nw[j];
  }

  float bj = act ? b[lane] : 0.f;
#pragma unroll
  for (int r = 0; r < 8; ++r) {
    int row = row0 + rbase + r;
    if (row < NN) {
      // all 64 lanes write z2 so the pad cols are ZERO (gather reads them)
      z2[(size_t)row * ZPAD + lane] = act ? accZ[r] : 0.f;
      s2p[(size_t)row * ZPAD + lane] = accS[r] + bj;  // pad lanes never read
    }
  }
}

// ---------------- layer 2 final: out = s2p + mean_neigh(z2) ----------------
__global__ __launch_bounds__(256) void k_agg2(const float* __restrict__ z2,
                                              const float* __restrict__ s2p,
                                              const int* __restrict__ indptr,
                                              const int* __restrict__ esrc,
                                              float* __restrict__ out) {
  int w = (blockIdx.x * 256 + threadIdx.x) >> 6;
  int lane = threadIdx.x & 63;
  if (w >= NN) return;
  int beg = indptr[w], end = indptr[w + 1];
  float a = 0.f;
  int e = beg;
  for (; e + 15 < end; e += 16) {
    int idx[16];
#pragma unroll
    for (int j = 0; j < 16; ++j) idx[j] = esrc[e + j];
    float v[16];
#pragma unroll
    for (int j = 0; j < 16; ++j) v[j] = z2[(size_t)idx[j] * ZPAD + lane];
#pragma unroll
    for (int j = 0; j < 16; ++j) a += v[j];
  }
  for (; e + 3 < end; e += 4) {
    int i0 = esrc[e], i1 = esrc[e + 1], i2 = esrc[e + 2], i3 = esrc[e + 3];
    a += z2[(size_t)i0 * ZPAD + lane] + z2[(size_t)i1 * ZPAD + lane] +
         z2[(size_t)i2 * ZPAD + lane] + z2[(size_t)i3 * ZPAD + lane];
  }
  for (; e < end; ++e) a += z2[(size_t)esrc[e] * ZPAD + lane];
  float inv = 1.0f / fmaxf((float)(end - beg), 1.0f);
  if (lane < NCLS)
    out[(size_t)w * NCLS + lane] = s2p[(size_t)w * ZPAD + lane] + a * inv;
}

// ---------------- launch ----------------
extern "C" void kernel_launch(void* const* d_in, const int* in_sizes, int n_in,
                              void* d_out, int out_size, void* d_ws, size_t ws_size,
                              hipStream_t stream) {
  (void)in_sizes; (void)n_in; (void)out_size; (void)ws_size;
  const float* x       = (const float*)d_in[0];
  const int*   src     = (const int*)d_in[1];
  const int*   dst     = (const int*)d_in[2];
  const float* w_self0 = (const float*)d_in[3];
  const float* w_nei0  = (const float*)d_in[4];
  const float* b0      = (const float*)d_in[5];
  const float* g0      = (const float*)d_in[6];
  const float* be0     = (const float*)d_in[7];
  const float* w_self1 = (const float*)d_in[8];
  const float* w_nei1  = (const float*)d_in[9];
  const float* b1      = (const float*)d_in[10];
  const float* g1      = (const float*)d_in[11];
  const float* be1     = (const float*)d_in[12];
  const float* w_self2 = (const float*)d_in[13];
  const float* w_nei2  = (const float*)d_in[14];
  const float* b2      = (const float*)d_in[15];
  float* outp = (float*)d_out;

  char* ws = (char*)d_ws;
  size_t off = 0;
  auto alloc = [&](size_t bytes) -> void* {
    off = (off + 255) & ~(size_t)255;
    void* p = ws + off;
    off += bytes;
    return p;
  };
  int*   counts = (int*)alloc(NN * sizeof(int));
  int*   indptr = (int*)alloc((NN + 1) * sizeof(int));
  int*   cursor = (int*)alloc(NN * sizeof(int));
  int*   bsum   = (int*)alloc(256 * sizeof(int));
  int*   esrc   = (int*)alloc(NE * sizeof(int));
  float* hn     = (float*)alloc((size_t)NN * D * sizeof(float));  // also z2 (layer 2)
  float* h1     = (float*)alloc((size_t)NN * D * sizeof(float));  // also s2p (layer 2)
  float* h2     = (float*)alloc((size_t)NN * D * sizeof(float));
  float* z2  = hn;  // 12.8 MB into 25.6 MB slot
  float* s2p = h1;  // h1 dead once h2 exists

  const int nbScan = (NN + 255) / 256;  // 196

  // CSR build
  hipMemsetAsync(counts, 0, NN * sizeof(int), stream);
  k_count<<<(NE + 255) / 256, 256, 0, stream>>>(dst, counts);
  k_scan1<<<nbScan, 256, 0, stream>>>(counts, indptr, bsum);
  k_scan2<<<1, 256, 0, stream>>>(bsum, nbScan);
  k_scan3<<<nbScan, 256, 0, stream>>>(indptr, bsum, cursor);
  k_scatter<<<(NE + 255) / 256, 256, 0, stream>>>(src, dst, cursor, esrc);

  const int aggBlocks  = (NN * 64) / 256;   // 12500
  const int gemmBlocks = (NN + 31) / 32;    // 1563

  // layer 0
  k_agg<<<aggBlocks, 256, 0, stream>>>(x, indptr, esrc, hn);
  k_gemm_ln<<<gemmBlocks, 256, 0, stream>>>(x, hn, w_self0, w_nei0, b0, g0, be0, h1);
  // layer 1
  k_agg<<<aggBlocks, 256, 0, stream>>>(h1, indptr, esrc, hn);
  k_gemm_ln<<<gemmBlocks, 256, 0, stream>>>(h1, hn, w_self1, w_nei1, b1, g1, be1, h2);
  // layer 2: project first (agg commutes with the linear map), then 64-wide agg
  k_gemm_proj2<<<gemmBlocks, 256, 0, stream>>>(h2, w_self2, w_nei2, b2, s2p, z2);
  k_agg2<<<aggBlocks, 256, 0, stream>>>(z2, s2p, indptr, esrc, outp);
}

// Round 12
// 488.695 us; speedup vs baseline: 2.4716x; 1.0043x over previous
//
#include <hip/hip_runtime.h>

#define NN 50000
#define NE 800000
#define D 128
#define NCLS 47
#define ZPAD 64   // padded width for projected layer-2 features
#define LN_EPS 1e-5f

// ---------------- CSR build ----------------
__global__ void k_count(const int* __restrict__ dst, int* __restrict__ counts) {
  int i = blockIdx.x * blockDim.x + threadIdx.x;
  if (i < NE) atomicAdd(&counts[dst[i]], 1);
}

__global__ void k_scan1(const int* __restrict__ counts, int* __restrict__ excl,
                        int* __restrict__ bsum) {
  __shared__ int tmp[256];
  int t = threadIdx.x, i = blockIdx.x * 256 + t;
  int v = (i < NN) ? counts[i] : 0;
  tmp[t] = v;
  __syncthreads();
  for (int off = 1; off < 256; off <<= 1) {
    int u = (t >= off) ? tmp[t - off] : 0;
    __syncthreads();
    tmp[t] += u;
    __syncthreads();
  }
  if (i < NN) excl[i] = tmp[t] - v;
  if (t == 255) bsum[blockIdx.x] = tmp[255];
}

__global__ void k_scan2(int* __restrict__ bsum, int nb) {
  __shared__ int tmp[256];
  int t = threadIdx.x;
  int v = (t < nb) ? bsum[t] : 0;
  tmp[t] = v;
  __syncthreads();
  for (int off = 1; off < 256; off <<= 1) {
    int u = (t >= off) ? tmp[t - off] : 0;
    __syncthreads();
    tmp[t] += u;
    __syncthreads();
  }
  if (t < nb) bsum[t] = tmp[t] - v;
}

__global__ void k_scan3(int* __restrict__ indptr, const int* __restrict__ bsum,
                        int* __restrict__ cursor) {
  int i = blockIdx.x * 256 + threadIdx.x;
  if (i < NN) {
    int v = indptr[i] + bsum[i >> 8];
    indptr[i] = v;
    cursor[i] = v;
  }
  if (i == 0) indptr[NN] = NE;
}

__global__ void k_scatter(const int* __restrict__ src, const int* __restrict__ dst,
                          int* __restrict__ cursor, int* __restrict__ esrc) {
  int i = blockIdx.x * blockDim.x + threadIdx.x;
  if (i < NE) {
    int d = dst[i];
    int pos = atomicAdd(&cursor[d], 1);
    esrc[pos] = src[i];
  }
}

// ---------------- mean aggregation (128-wide): ONE WAVE PER BLOCK ----------------
// 64-thread blocks: each node retires independently (no intra-block straggler
// coupling; degree ~Poisson(16) made 4-wave blocks wait on E[max of 4] ~ 1.3x mean).
// Same loads and sum order as the measured R10 kernel -> bit-identical output.
__global__ __launch_bounds__(64) void k_agg(const float* __restrict__ feat,
                                            const int* __restrict__ indptr,
                                            const int* __restrict__ esrc,
                                            float* __restrict__ out) {
  int w = blockIdx.x;
  int lane = threadIdx.x;
  if (w >= NN) return;
  int beg = indptr[w], end = indptr[w + 1];
  float a0 = 0.f, a1 = 0.f;
  int e = beg;
  for (; e + 15 < end; e += 16) {  // 16 independent gather chains in flight
    int idx[16];
#pragma unroll
    for (int j = 0; j < 16; ++j) idx[j] = esrc[e + j];
    float2 v[16];
#pragma unroll
    for (int j = 0; j < 16; ++j)
      v[j] = *(const float2*)(feat + (size_t)idx[j] * D + lane * 2);
#pragma unroll
    for (int j = 0; j < 16; ++j) { a0 += v[j].x; a1 += v[j].y; }
  }
  for (; e + 3 < end; e += 4) {
    int i0 = esrc[e], i1 = esrc[e + 1], i2 = esrc[e + 2], i3 = esrc[e + 3];
    float2 v0 = *(const float2*)(feat + (size_t)i0 * D + lane * 2);
    float2 v1 = *(const float2*)(feat + (size_t)i1 * D + lane * 2);
    float2 v2 = *(const float2*)(feat + (size_t)i2 * D + lane * 2);
    float2 v3 = *(const float2*)(feat + (size_t)i3 * D + lane * 2);
    a0 += v0.x + v1.x + v2.x + v3.x;
    a1 += v0.y + v1.y + v2.y + v3.y;
  }
  for (; e < end; ++e) {
    float2 v0 = *(const float2*)(feat + (size_t)esrc[e] * D + lane * 2);
    a0 += v0.x;
    a1 += v0.y;
  }
  float inv = 1.0f / fmaxf((float)(end - beg), 1.0f);
  float2 o;
  o.x = a0 * inv;
  o.y = a1 * inv;
  *(float2*)(out + (size_t)w * D + lane * 2) = o;
}

// ---------------- fused dual-GEMM + LN + ReLU (hidden layers) ----------------
// 32 rows/block (32 KB LDS), 256 thr (4 waves), wave handles 8 rows, lane j
// owns cols j and j+64. Per chunk: batch all 8 rows' ds_read_b128 first
// (8 outstanding), then 64 FMAs. Weights pipelined 1 chunk ahead.
// (256,4): VGPR cap 128; the hv[8]+cw+nw+acc working set (~64 live) NEEDS
// this headroom — (256,5) capped regs at 48, serialized the loads and
// spilled (measured R9: 129 µs vs 72.9 µs). DO NOT change the bound.
__global__ __launch_bounds__(256, 4) void k_gemm_ln(
    const float* __restrict__ h, const float* __restrict__ hn,
    const float* __restrict__ ws, const float* __restrict__ wn,
    const float* __restrict__ b, const float* __restrict__ g,
    const float* __restrict__ be, float* __restrict__ out) {
  __shared__ float lds[32][256];  // cols [0,128)=h, [128,256)=hn (32 KB)
  int tid = threadIdx.x;
  int row0 = blockIdx.x * 32;
  for (int i = tid; i < 32 * 64; i += 256) {  // float4 granules, 64 per row
    int r = i >> 6, q = i & 63;
    int row = row0 + r;
    float4 v = make_float4(0.f, 0.f, 0.f, 0.f);
    if (row < NN) {
      const float* p = (q < 32) ? (h + (size_t)row * D + q * 4)
                                : (hn + (size_t)row * D + (q - 32) * 4);
      v = *(const float4*)p;
    }
    *(float4*)&lds[r][q * 4] = v;
  }
  __syncthreads();

  int wv = tid >> 6, lane = tid & 63;
  int rbase = wv * 8;
  float acc0[8], acc1[8];
#pragma unroll
  for (int r = 0; r < 8; ++r) { acc0[r] = 0.f; acc1[r] = 0.f; }

  // 64 chunks of 4 k-rows: c in [0,32) -> ws, [32,64) -> wn; lds col = c*4.
  float cw[8], nw[8];
#pragma unroll
  for (int j = 0; j < 4; ++j) {  // preload chunk 0 (self rows 0..3)
    cw[2 * j]     = ws[j * 128 + lane];
    cw[2 * j + 1] = ws[j * 128 + lane + 64];
  }
#pragma unroll 2
  for (int c = 0; c < 64; ++c) {
    int cn = (c + 1 < 64) ? c + 1 : 63;  // last iter: harmless reload
    const float* np = ((cn & 32) ? wn : ws) + (cn & 31) * 512;
    // batch-load current chunk's 8 rows -> 8 ds_read_b128 in flight
    float4 hv[8];
#pragma unroll
    for (int r = 0; r < 8; ++r) hv[r] = *(const float4*)&lds[rbase + r][c * 4];
    // prefetch next chunk's weights (8 global loads in flight over the FMAs)
#pragma unroll
    for (int j = 0; j < 4; ++j) {
      nw[2 * j]     = np[j * 128 + lane];
      nw[2 * j + 1] = np[j * 128 + lane + 64];
    }
#pragma unroll
    for (int r = 0; r < 8; ++r) {
      acc0[r] = fmaf(hv[r].x, cw[0], acc0[r]);
      acc1[r] = fmaf(hv[r].x, cw[1], acc1[r]);
      acc0[r] = fmaf(hv[r].y, cw[2], acc0[r]);
      acc1[r] = fmaf(hv[r].y, cw[3], acc1[r]);
      acc0[r] = fmaf(hv[r].z, cw[4], acc0[r]);
      acc1[r] = fmaf(hv[r].z, cw[5], acc1[r]);
      acc0[r] = fmaf(hv[r].w, cw[6], acc0[r]);
      acc1[r] = fmaf(hv[r].w, cw[7], acc1[r]);
    }
#pragma unroll
    for (int j = 0; j < 8; ++j) cw[j] = nw[j];
  }

  float bj0 = b[lane], bj1 = b[lane + 64];
  float gj0 = g[lane], gj1 = g[lane + 64];
  float ej0 = be[lane], ej1 = be[lane + 64];
#pragma unroll
  for (int r = 0; r < 8; ++r) {
    float v0 = acc0[r] + bj0, v1 = acc1[r] + bj1;
    float s = v0 + v1, q2 = v0 * v0 + v1 * v1;
#pragma unroll
    for (int off = 1; off < 64; off <<= 1) {
      s += __shfl_xor(s, off, 64);
      q2 += __shfl_xor(q2, off, 64);
    }
    float mu = s * (1.0f / 128.0f);
    float var = q2 * (1.0f / 128.0f) - mu * mu;
    float rs = rsqrtf(var + LN_EPS);
    float o0 = fmaxf((v0 - mu) * rs * gj0 + ej0, 0.f);
    float o1 = fmaxf((v1 - mu) * rs * gj1 + ej1, 0.f);
    int row = row0 + rbase + r;
    if (row < NN) {
      out[(size_t)row * D + lane] = o0;
      out[(size_t)row * D + lane + 64] = o1;
    }
  }
}

// ---------------- layer 2: project h2 through BOTH weight matrices ----------------
// s2p[row][j] = (h2 @ w_self2)[row][j] + b2[j]   (j < 47)
// z2 [row][j] = (h2 @ w_neigh2)[row][j]          (j < 47; cols 47..63 zeroed)
// (256,4): VGPR cap 128 -- hv[8]+cw+nw+accs fit, NO spill (see R8 disaster at (256,8)).
__global__ __launch_bounds__(256, 4) void k_gemm_proj2(
    const float* __restrict__ h, const float* __restrict__ ws,
    const float* __restrict__ wn, const float* __restrict__ b,
    float* __restrict__ s2p, float* __restrict__ z2) {
  __shared__ float lds[32][128];  // 16 KB
  int tid = threadIdx.x;
  int row0 = blockIdx.x * 32;
  for (int i = tid; i < 32 * 32; i += 256) {  // float4 granules, 32 per row
    int r = i >> 5, q = i & 31;
    int row = row0 + r;
    float4 v = make_float4(0.f, 0.f, 0.f, 0.f);
    if (row < NN) v = *(const float4*)(h + (size_t)row * D + q * 4);
    *(float4*)&lds[r][q * 4] = v;
  }
  __syncthreads();

  int wv = tid >> 6, lane = tid & 63;
  int rbase = wv * 8;
  bool act = lane < NCLS;
  float accS[8], accZ[8];
#pragma unroll
  for (int r = 0; r < 8; ++r) { accS[r] = 0.f; accZ[r] = 0.f; }

  // 32 chunks of 4 k-rows; cw[0..3]=self rows, cw[4..7]=neigh rows.
  float cw[8], nw[8];
#pragma unroll
  for (int j = 0; j < 4; ++j) {
    cw[j]     = act ? ws[j * NCLS + lane] : 0.f;
    cw[4 + j] = act ? wn[j * NCLS + lane] : 0.f;
  }
#pragma unroll 2
  for (int c = 0; c < 32; ++c) {
    int cn = (c + 1 < 32) ? c + 1 : 31;
    // batch-load current chunk's 8 rows
    float4 hv[8];
#pragma unroll
    for (int r = 0; r < 8; ++r) hv[r] = *(const float4*)&lds[rbase + r][c * 4];
#pragma unroll
    for (int j = 0; j < 4; ++j) {
      nw[j]     = act ? ws[(cn * 4 + j) * NCLS + lane] : 0.f;
      nw[4 + j] = act ? wn[(cn * 4 + j) * NCLS + lane] : 0.f;
    }
#pragma unroll
    for (int r = 0; r < 8; ++r) {
      accS[r] = fmaf(hv[r].x, cw[0], accS[r]);
      accZ[r] = fmaf(hv[r].x, cw[4], accZ[r]);
      accS[r] = fmaf(hv[r].y, cw[1], accS[r]);
      accZ[r] = fmaf(hv[r].y, cw[5], accZ[r]);
      accS[r] = fmaf(hv[r].z, cw[2], accS[r]);
      accZ[r] = fmaf(hv[r].z, cw[6], accZ[r]);
      accS[r] = fmaf(hv[r].w, cw[3], accS[r]);
      accZ[r] = fmaf(hv[r].w, cw[7], accZ[r]);
    }
#pragma unroll
    for (int j = 0; j < 8; ++j) cw[j] = nw[j];
  }

  float bj = act ? b[lane] : 0.f;
#pragma unroll
  for (int r = 0; r < 8; ++r) {
    int row = row0 + rbase + r;
    if (row < NN) {
      // all 64 lanes write z2 so the pad cols are ZERO (gather reads them)
      z2[(size_t)row * ZPAD + lane] = act ? accZ[r] : 0.f;
      s2p[(size_t)row * ZPAD + lane] = accS[r] + bj;  // pad lanes never read
    }
  }
}

// ---------------- layer 2 final: out = s2p + mean_neigh(z2), 1 wave/block ----------------
__global__ __launch_bounds__(64) void k_agg2(const float* __restrict__ z2,
                                             const float* __restrict__ s2p,
                                             const int* __restrict__ indptr,
                                             const int* __restrict__ esrc,
                                             float* __restrict__ out) {
  int w = blockIdx.x;
  int lane = threadIdx.x;
  if (w >= NN) return;
  int beg = indptr[w], end = indptr[w + 1];
  float a = 0.f;
  int e = beg;
  for (; e + 15 < end; e += 16) {
    int idx[16];
#pragma unroll
    for (int j = 0; j < 16; ++j) idx[j] = esrc[e + j];
    float v[16];
#pragma unroll
    for (int j = 0; j < 16; ++j) v[j] = z2[(size_t)idx[j] * ZPAD + lane];
#pragma unroll
    for (int j = 0; j < 16; ++j) a += v[j];
  }
  for (; e + 3 < end; e += 4) {
    int i0 = esrc[e], i1 = esrc[e + 1], i2 = esrc[e + 2], i3 = esrc[e + 3];
    a += z2[(size_t)i0 * ZPAD + lane] + z2[(size_t)i1 * ZPAD + lane] +
         z2[(size_t)i2 * ZPAD + lane] + z2[(size_t)i3 * ZPAD + lane];
  }
  for (; e < end; ++e) a += z2[(size_t)esrc[e] * ZPAD + lane];
  float inv = 1.0f / fmaxf((float)(end - beg), 1.0f);
  if (lane < NCLS)
    out[(size_t)w * NCLS + lane] = s2p[(size_t)w * ZPAD + lane] + a * inv;
}

// ---------------- launch ----------------
extern "C" void kernel_launch(void* const* d_in, const int* in_sizes, int n_in,
                              void* d_out, int out_size, void* d_ws, size_t ws_size,
                              hipStream_t stream) {
  (void)in_sizes; (void)n_in; (void)out_size; (void)ws_size;
  const float* x       = (const float*)d_in[0];
  const int*   src     = (const int*)d_in[1];
  const int*   dst     = (const int*)d_in[2];
  const float* w_self0 = (const float*)d_in[3];
  const float* w_nei0  = (const float*)d_in[4];
  const float* b0      = (const float*)d_in[5];
  const float* g0      = (const float*)d_in[6];
  const float* be0     = (const float*)d_in[7];
  const float* w_self1 = (const float*)d_in[8];
  const float* w_nei1  = (const float*)d_in[9];
  const float* b1      = (const float*)d_in[10];
  const float* g1      = (const float*)d_in[11];
  const float* be1     = (const float*)d_in[12];
  const float* w_self2 = (const float*)d_in[13];
  const float* w_nei2  = (const float*)d_in[14];
  const float* b2      = (const float*)d_in[15];
  float* outp = (float*)d_out;

  char* ws = (char*)d_ws;
  size_t off = 0;
  auto alloc = [&](size_t bytes) -> void* {
    off = (off + 255) & ~(size_t)255;
    void* p = ws + off;
    off += bytes;
    return p;
  };
  int*   counts = (int*)alloc(NN * sizeof(int));
  int*   indptr = (int*)alloc((NN + 1) * sizeof(int));
  int*   cursor = (int*)alloc(NN * sizeof(int));
  int*   bsum   = (int*)alloc(256 * sizeof(int));
  int*   esrc   = (int*)alloc(NE * sizeof(int));
  float* hn     = (float*)alloc((size_t)NN * D * sizeof(float));  // also z2 (layer 2)
  float* h1     = (float*)alloc((size_t)NN * D * sizeof(float));  // also s2p (layer 2)
  float* h2     = (float*)alloc((size_t)NN * D * sizeof(float));
  float* z2  = hn;  // 12.8 MB into 25.6 MB slot
  float* s2p = h1;  // h1 dead once h2 exists

  const int nbScan = (NN + 255) / 256;  // 196

  // CSR build
  hipMemsetAsync(counts, 0, NN * sizeof(int), stream);
  k_count<<<(NE + 255) / 256, 256, 0, stream>>>(dst, counts);
  k_scan1<<<nbScan, 256, 0, stream>>>(counts, indptr, bsum);
  k_scan2<<<1, 256, 0, stream>>>(bsum, nbScan);
  k_scan3<<<nbScan, 256, 0, stream>>>(indptr, bsum, cursor);
  k_scatter<<<(NE + 255) / 256, 256, 0, stream>>>(src, dst, cursor, esrc);

  const int gemmBlocks = (NN + 31) / 32;    // 1563

  // layer 0
  k_agg<<<NN, 64, 0, stream>>>(x, indptr, esrc, hn);
  k_gemm_ln<<<gemmBlocks, 256, 0, stream>>>(x, hn, w_self0, w_nei0, b0, g0, be0, h1);
  // layer 1
  k_agg<<<NN, 64, 0, stream>>>(h1, indptr, esrc, hn);
  k_gemm_ln<<<gemmBlocks, 256, 0, stream>>>(h1, hn, w_self1, w_nei1, b1, g1, be1, h2);
  // layer 2: project first (agg commutes with the linear map), then 64-wide agg
  k_gemm_proj2<<<gemmBlocks, 256, 0, stream>>>(h2, w_self2, w_nei2, b2, s2p, z2);
  k_agg2<<<NN, 64, 0, stream>>>(z2, s2p, indptr, esrc, outp);
}

// Round 13
// 481.503 us; speedup vs baseline: 2.5086x; 1.0149x over previous
//
#include <hip/hip_runtime.h>

#define NN 50000
#define NE 800000
#define D 128
#define NCLS 47
#define ZPAD 64   // padded width for projected layer-2 features
#define LN_EPS 1e-5f

// ---------------- CSR build ----------------
__global__ void k_count(const int* __restrict__ dst, int* __restrict__ counts) {
  int i = blockIdx.x * blockDim.x + threadIdx.x;
  if (i < NE) atomicAdd(&counts[dst[i]], 1);
}

__global__ void k_scan1(const int* __restrict__ counts, int* __restrict__ excl,
                        int* __restrict__ bsum) {
  __shared__ int tmp[256];
  int t = threadIdx.x, i = blockIdx.x * 256 + t;
  int v = (i < NN) ? counts[i] : 0;
  tmp[t] = v;
  __syncthreads();
  for (int off = 1; off < 256; off <<= 1) {
    int u = (t >= off) ? tmp[t - off] : 0;
    __syncthreads();
    tmp[t] += u;
    __syncthreads();
  }
  if (i < NN) excl[i] = tmp[t] - v;
  if (t == 255) bsum[blockIdx.x] = tmp[255];
}

__global__ void k_scan2(int* __restrict__ bsum, int nb) {
  __shared__ int tmp[256];
  int t = threadIdx.x;
  int v = (t < nb) ? bsum[t] : 0;
  tmp[t] = v;
  __syncthreads();
  for (int off = 1; off < 256; off <<= 1) {
    int u = (t >= off) ? tmp[t - off] : 0;
    __syncthreads();
    tmp[t] += u;
    __syncthreads();
  }
  if (t < nb) bsum[t] = tmp[t] - v;
}

__global__ void k_scan3(int* __restrict__ indptr, const int* __restrict__ bsum,
                        int* __restrict__ cursor) {
  int i = blockIdx.x * 256 + threadIdx.x;
  if (i < NN) {
    int v = indptr[i] + bsum[i >> 8];
    indptr[i] = v;
    cursor[i] = v;
  }
  if (i == 0) indptr[NN] = NE;
}

__global__ void k_scatter(const int* __restrict__ src, const int* __restrict__ dst,
                          int* __restrict__ cursor, int* __restrict__ esrc) {
  int i = blockIdx.x * blockDim.x + threadIdx.x;
  if (i < NE) {
    int d = dst[i];
    int pos = atomicAdd(&cursor[d], 1);
    esrc[pos] = src[i];
  }
}

// ---------------- FUSED: gather-mean + dual-GEMM + LN + ReLU (hidden layers) ----------------
// 32 rows/block, 256 thr (4 waves). Phase 1: stage self rows into lds[r][0..128).
// Phase 2: each wave gathers neighbor means for its 8 rows into lds[r][128..256)
// (same edge order + float2/lane layout as the old k_agg -> bit-identical).
// Phase 3: GEMM, batched ds_read_b128 (8 in flight), weights pipelined 1 ahead.
// Cross-block phase skew overlaps gather latency with other blocks' FMA phases,
// and the hn HBM round-trip (51 MB/layer) is eliminated.
// (256,4): VGPR cap 128; working set ~64 live NEEDS this headroom (R9: (256,5)
// capped regs at 48 -> serialized + spilled, 129 vs 72.9 us). DO NOT change.
__global__ __launch_bounds__(256, 4) void k_sage_ln(
    const float* __restrict__ h, const int* __restrict__ indptr,
    const int* __restrict__ esrc,
    const float* __restrict__ ws, const float* __restrict__ wn,
    const float* __restrict__ b, const float* __restrict__ g,
    const float* __restrict__ be, float* __restrict__ out) {
  __shared__ float lds[32][256];  // cols [0,128)=h, [128,256)=gathered mean (32 KB)
  int tid = threadIdx.x;
  int row0 = blockIdx.x * 32;
  int wv = tid >> 6, lane = tid & 63;
  int rbase = wv * 8;

  // Phase 1: stage self rows (coalesced float4; 32 rows x 32 granules / 256 thr)
  for (int i = tid; i < 32 * 32; i += 256) {
    int r = i >> 5, q = i & 31;
    int row = row0 + r;
    float4 v = make_float4(0.f, 0.f, 0.f, 0.f);
    if (row < NN) v = *(const float4*)(h + (size_t)row * D + q * 4);
    *(float4*)&lds[r][q * 4] = v;
  }

  // Phase 2: gather-mean neighbors for this wave's 8 rows (k_agg's exact order)
  for (int i = 0; i < 8; ++i) {
    int node = row0 + rbase + i;
    float a0 = 0.f, a1 = 0.f;
    if (node < NN) {
      int beg = indptr[node], end = indptr[node + 1];
      int e = beg;
      for (; e + 15 < end; e += 16) {  // 16 independent gather chains
        int idx[16];
#pragma unroll
        for (int j = 0; j < 16; ++j) idx[j] = esrc[e + j];
        float2 v[16];
#pragma unroll
        for (int j = 0; j < 16; ++j)
          v[j] = *(const float2*)(h + (size_t)idx[j] * D + lane * 2);
#pragma unroll
        for (int j = 0; j < 16; ++j) { a0 += v[j].x; a1 += v[j].y; }
      }
      for (; e + 3 < end; e += 4) {
        int i0 = esrc[e], i1 = esrc[e + 1], i2 = esrc[e + 2], i3 = esrc[e + 3];
        float2 v0 = *(const float2*)(h + (size_t)i0 * D + lane * 2);
        float2 v1 = *(const float2*)(h + (size_t)i1 * D + lane * 2);
        float2 v2 = *(const float2*)(h + (size_t)i2 * D + lane * 2);
        float2 v3 = *(const float2*)(h + (size_t)i3 * D + lane * 2);
        a0 += v0.x + v1.x + v2.x + v3.x;
        a1 += v0.y + v1.y + v2.y + v3.y;
      }
      for (; e < end; ++e) {
        float2 v0 = *(const float2*)(h + (size_t)esrc[e] * D + lane * 2);
        a0 += v0.x;
        a1 += v0.y;
      }
      float inv = 1.0f / fmaxf((float)(end - beg), 1.0f);
      a0 *= inv;
      a1 *= inv;
    }
    float2 o; o.x = a0; o.y = a1;
    *(float2*)&lds[rbase + i][128 + lane * 2] = o;  // ds_write_b64, 2-way free
  }
  __syncthreads();

  // Phase 3: GEMM. 64 chunks of 4 k-rows: c in [0,32) -> ws, [32,64) -> wn.
  float acc0[8], acc1[8];
#pragma unroll
  for (int r = 0; r < 8; ++r) { acc0[r] = 0.f; acc1[r] = 0.f; }

  float cw[8], nw[8];
#pragma unroll
  for (int j = 0; j < 4; ++j) {  // preload chunk 0 (self rows 0..3)
    cw[2 * j]     = ws[j * 128 + lane];
    cw[2 * j + 1] = ws[j * 128 + lane + 64];
  }
#pragma unroll 2
  for (int c = 0; c < 64; ++c) {
    int cn = (c + 1 < 64) ? c + 1 : 63;  // last iter: harmless reload
    const float* np = ((cn & 32) ? wn : ws) + (cn & 31) * 512;
    float4 hv[8];
#pragma unroll
    for (int r = 0; r < 8; ++r) hv[r] = *(const float4*)&lds[rbase + r][c * 4];
#pragma unroll
    for (int j = 0; j < 4; ++j) {
      nw[2 * j]     = np[j * 128 + lane];
      nw[2 * j + 1] = np[j * 128 + lane + 64];
    }
#pragma unroll
    for (int r = 0; r < 8; ++r) {
      acc0[r] = fmaf(hv[r].x, cw[0], acc0[r]);
      acc1[r] = fmaf(hv[r].x, cw[1], acc1[r]);
      acc0[r] = fmaf(hv[r].y, cw[2], acc0[r]);
      acc1[r] = fmaf(hv[r].y, cw[3], acc1[r]);
      acc0[r] = fmaf(hv[r].z, cw[4], acc0[r]);
      acc1[r] = fmaf(hv[r].z, cw[5], acc1[r]);
      acc0[r] = fmaf(hv[r].w, cw[6], acc0[r]);
      acc1[r] = fmaf(hv[r].w, cw[7], acc1[r]);
    }
#pragma unroll
    for (int j = 0; j < 8; ++j) cw[j] = nw[j];
  }

  float bj0 = b[lane], bj1 = b[lane + 64];
  float gj0 = g[lane], gj1 = g[lane + 64];
  float ej0 = be[lane], ej1 = be[lane + 64];
#pragma unroll
  for (int r = 0; r < 8; ++r) {
    float v0 = acc0[r] + bj0, v1 = acc1[r] + bj1;
    float s = v0 + v1, q2 = v0 * v0 + v1 * v1;
#pragma unroll
    for (int off = 1; off < 64; off <<= 1) {
      s += __shfl_xor(s, off, 64);
      q2 += __shfl_xor(q2, off, 64);
    }
    float mu = s * (1.0f / 128.0f);
    float var = q2 * (1.0f / 128.0f) - mu * mu;
    float rs = rsqrtf(var + LN_EPS);
    float o0 = fmaxf((v0 - mu) * rs * gj0 + ej0, 0.f);
    float o1 = fmaxf((v1 - mu) * rs * gj1 + ej1, 0.f);
    int row = row0 + rbase + r;
    if (row < NN) {
      out[(size_t)row * D + lane] = o0;
      out[(size_t)row * D + lane + 64] = o1;
    }
  }
}

// ---------------- layer 2: project h2 through BOTH weight matrices ----------------
// (256,4): VGPR cap 128 -- fits, NO spill (R8 disaster at (256,8) is the warning).
__global__ __launch_bounds__(256, 4) void k_gemm_proj2(
    const float* __restrict__ h, const float* __restrict__ ws,
    const float* __restrict__ wn, const float* __restrict__ b,
    float* __restrict__ s2p, float* __restrict__ z2) {
  __shared__ float lds[32][128];  // 16 KB
  int tid = threadIdx.x;
  int row0 = blockIdx.x * 32;
  for (int i = tid; i < 32 * 32; i += 256) {
    int r = i >> 5, q = i & 31;
    int row = row0 + r;
    float4 v = make_float4(0.f, 0.f, 0.f, 0.f);
    if (row < NN) v = *(const float4*)(h + (size_t)row * D + q * 4);
    *(float4*)&lds[r][q * 4] = v;
  }
  __syncthreads();

  int wv = tid >> 6, lane = tid & 63;
  int rbase = wv * 8;
  bool act = lane < NCLS;
  float accS[8], accZ[8];
#pragma unroll
  for (int r = 0; r < 8; ++r) { accS[r] = 0.f; accZ[r] = 0.f; }

  float cw[8], nw[8];
#pragma unroll
  for (int j = 0; j < 4; ++j) {
    cw[j]     = act ? ws[j * NCLS + lane] : 0.f;
    cw[4 + j] = act ? wn[j * NCLS + lane] : 0.f;
  }
#pragma unroll 2
  for (int c = 0; c < 32; ++c) {
    int cn = (c + 1 < 32) ? c + 1 : 31;
    float4 hv[8];
#pragma unroll
    for (int r = 0; r < 8; ++r) hv[r] = *(const float4*)&lds[rbase + r][c * 4];
#pragma unroll
    for (int j = 0; j < 4; ++j) {
      nw[j]     = act ? ws[(cn * 4 + j) * NCLS + lane] : 0.f;
      nw[4 + j] = act ? wn[(cn * 4 + j) * NCLS + lane] : 0.f;
    }
#pragma unroll
    for (int r = 0; r < 8; ++r) {
      accS[r] = fmaf(hv[r].x, cw[0], accS[r]);
      accZ[r] = fmaf(hv[r].x, cw[4], accZ[r]);
      accS[r] = fmaf(hv[r].y, cw[1], accS[r]);
      accZ[r] = fmaf(hv[r].y, cw[5], accZ[r]);
      accS[r] = fmaf(hv[r].z, cw[2], accS[r]);
      accZ[r] = fmaf(hv[r].z, cw[6], accZ[r]);
      accS[r] = fmaf(hv[r].w, cw[3], accS[r]);
      accZ[r] = fmaf(hv[r].w, cw[7], accZ[r]);
    }
#pragma unroll
    for (int j = 0; j < 8; ++j) cw[j] = nw[j];
  }

  float bj = act ? b[lane] : 0.f;
#pragma unroll
  for (int r = 0; r < 8; ++r) {
    int row = row0 + rbase + r;
    if (row < NN) {
      z2[(size_t)row * ZPAD + lane] = act ? accZ[r] : 0.f;  // pad cols ZERO
      s2p[(size_t)row * ZPAD + lane] = accS[r] + bj;
    }
  }
}

// ---------------- layer 2 final: out = s2p + mean_neigh(z2), 1 wave/block ----------------
__global__ __launch_bounds__(64) void k_agg2(const float* __restrict__ z2,
                                             const float* __restrict__ s2p,
                                             const int* __restrict__ indptr,
                                             const int* __restrict__ esrc,
                                             float* __restrict__ out) {
  int w = blockIdx.x;
  int lane = threadIdx.x;
  if (w >= NN) return;
  int beg = indptr[w], end = indptr[w + 1];
  float a = 0.f;
  int e = beg;
  for (; e + 15 < end; e += 16) {
    int idx[16];
#pragma unroll
    for (int j = 0; j < 16; ++j) idx[j] = esrc[e + j];
    float v[16];
#pragma unroll
    for (int j = 0; j < 16; ++j) v[j] = z2[(size_t)idx[j] * ZPAD + lane];
#pragma unroll
    for (int j = 0; j < 16; ++j) a += v[j];
  }
  for (; e + 3 < end; e += 4) {
    int i0 = esrc[e], i1 = esrc[e + 1], i2 = esrc[e + 2], i3 = esrc[e + 3];
    a += z2[(size_t)i0 * ZPAD + lane] + z2[(size_t)i1 * ZPAD + lane] +
         z2[(size_t)i2 * ZPAD + lane] + z2[(size_t)i3 * ZPAD + lane];
  }
  for (; e < end; ++e) a += z2[(size_t)esrc[e] * ZPAD + lane];
  float inv = 1.0f / fmaxf((float)(end - beg), 1.0f);
  if (lane < NCLS)
    out[(size_t)w * NCLS + lane] = s2p[(size_t)w * ZPAD + lane] + a * inv;
}

// ---------------- launch ----------------
extern "C" void kernel_launch(void* const* d_in, const int* in_sizes, int n_in,
                              void* d_out, int out_size, void* d_ws, size_t ws_size,
                              hipStream_t stream) {
  (void)in_sizes; (void)n_in; (void)out_size; (void)ws_size;
  const float* x       = (const float*)d_in[0];
  const int*   src     = (const int*)d_in[1];
  const int*   dst     = (const int*)d_in[2];
  const float* w_self0 = (const float*)d_in[3];
  const float* w_nei0  = (const float*)d_in[4];
  const float* b0      = (const float*)d_in[5];
  const float* g0      = (const float*)d_in[6];
  const float* be0     = (const float*)d_in[7];
  const float* w_self1 = (const float*)d_in[8];
  const float* w_nei1  = (const float*)d_in[9];
  const float* b1      = (const float*)d_in[10];
  const float* g1      = (const float*)d_in[11];
  const float* be1     = (const float*)d_in[12];
  const float* w_self2 = (const float*)d_in[13];
  const float* w_nei2  = (const float*)d_in[14];
  const float* b2      = (const float*)d_in[15];
  float* outp = (float*)d_out;

  char* ws = (char*)d_ws;
  size_t off = 0;
  auto alloc = [&](size_t bytes) -> void* {
    off = (off + 255) & ~(size_t)255;
    void* p = ws + off;
    off += bytes;
    return p;
  };
  int*   counts = (int*)alloc(NN * sizeof(int));
  int*   indptr = (int*)alloc((NN + 1) * sizeof(int));
  int*   cursor = (int*)alloc(NN * sizeof(int));
  int*   bsum   = (int*)alloc(256 * sizeof(int));
  int*   esrc   = (int*)alloc(NE * sizeof(int));
  float* h1     = (float*)alloc((size_t)NN * D * sizeof(float));  // also s2p (layer 2)
  float* h2     = (float*)alloc((size_t)NN * D * sizeof(float));
  float* z2     = (float*)alloc((size_t)NN * ZPAD * sizeof(float));
  float* s2p = h1;  // h1 dead once h2 exists

  const int nbScan = (NN + 255) / 256;  // 196

  // CSR build
  hipMemsetAsync(counts, 0, NN * sizeof(int), stream);
  k_count<<<(NE + 255) / 256, 256, 0, stream>>>(dst, counts);
  k_scan1<<<nbScan, 256, 0, stream>>>(counts, indptr, bsum);
  k_scan2<<<1, 256, 0, stream>>>(bsum, nbScan);
  k_scan3<<<nbScan, 256, 0, stream>>>(indptr, bsum, cursor);
  k_scatter<<<(NE + 255) / 256, 256, 0, stream>>>(src, dst, cursor, esrc);

  const int gemmBlocks = (NN + 31) / 32;  // 1563

  // layers 0,1: fused gather + GEMM + LN + ReLU
  k_sage_ln<<<gemmBlocks, 256, 0, stream>>>(x, indptr, esrc, w_self0, w_nei0,
                                            b0, g0, be0, h1);
  k_sage_ln<<<gemmBlocks, 256, 0, stream>>>(h1, indptr, esrc, w_self1, w_nei1,
                                            b1, g1, be1, h2);
  // layer 2: project first (agg commutes with the linear map), then 64-wide agg
  k_gemm_proj2<<<gemmBlocks, 256, 0, stream>>>(h2, w_self2, w_nei2, b2, s2p, z2);
  k_agg2<<<NN, 64, 0, stream>>>(z2, s2p, indptr, esrc, outp);
}